// Round 9
// baseline (545.029 us; speedup 1.0000x reference)
//
#include <hip/hip_runtime.h>

#define B_ 2048
#define T_ 2048
#define SPB 32    // samples per block: two independent groups of 16
#define GSTR 162  // per-g word stride in exchange buf (16 samples * 10 + 2 pad)
#define QT 256    // timesteps per x staging pass
#define XSTR 260  // f32 stride per sample row in x LDS (2-way banks, 16B aligned)

typedef _Float16 f16x8 __attribute__((ext_vector_type(8)));
typedef float    f32x4 __attribute__((ext_vector_type(4)));
typedef unsigned u32x2 __attribute__((ext_vector_type(2)));
typedef unsigned u32x4 __attribute__((ext_vector_type(4)));

__device__ __forceinline__ unsigned pkrtz(float lo, float hi) {
    return __builtin_bit_cast(unsigned, __builtin_amdgcn_cvt_pkrtz(lo, hi));
}

// Round 9 = round 7 (343 us, proven) interleaved over TWO independent sample
// groups per block. r7/r8 evidence: each step is ~150 cyc issue + ~260 cyc
// unfillable dependency stall (barrier + ds_read ~120 + chained MFMA + tanh),
// and r8 proved the per-step structure can't be shortened from source. So
// fill group A's stall with group B's issue work: one barrier steps BOTH
// groups (each has its own double-buffered exchange + h state + x rows).
// Per-group step code is byte-for-byte r7 (chained MFMA, ci post-barrier,
// direct x read -- every r8 change reverted). 64 blocks x 32 samples.
__global__ __launch_bounds__(256)
void rnn_mfma_2g(
    const float* __restrict__ x, const float* __restrict__ W_ih,
    const float* __restrict__ W_hh, const float* __restrict__ b_ih,
    const float* __restrict__ b_hh, const float* __restrict__ W_fc,
    const float* __restrict__ b_fc, float* __restrict__ out)
{
    __shared__ __align__(16) float xl[SPB * XSTR];         // ~33 KB x stage
    __shared__ __align__(16) unsigned ex[2][2][4 * GSTR];  // [grp][buf][g][s][10w]
    __shared__ float fcb[4][SPB];

    const int tid = threadIdx.x;
    const int w = tid >> 6;          // wave index == tile index (rows 16w+..)
    const int l = tid & 63;
    const int s = l & 15;            // sample column (C-col / A-M-row / B-N)
    const int g = l >> 4;            // slot group; C row-quad selector
    const int sb = blockIdx.x * SPB;
    const float L2E2 = 2.8853900817779268f;  // 2*log2(e), folded into W/bias

    // ---- A-frags for tile w (shared by both groups): slot (g,j) of chunk c
    // holds k = sigma_c(g,j) = 16*(2c+(j>>2)) + 4g + (j&3).  [HW-verified]
    f16x8 a0, a1;
#pragma unroll
    for (int j = 0; j < 8; ++j) {
        const int k0 = 16 * (0 + (j >> 2)) + 4 * g + (j & 3);
        const int k1 = 16 * (2 + (j >> 2)) + 4 * g + (j & 3);
        a0[j] = (_Float16)(W_hh[(16 * w + s) * 64 + k0] * L2E2);
        a1[j] = (_Float16)(W_hh[(16 * w + s) * 64 + k1] * L2E2);
    }

    // ---- per-lane C-slot constants: rows 16w + 4g + r
    float wih[4], bw[4];
#pragma unroll
    for (int r = 0; r < 4; ++r) {
        const int row = 16 * w + 4 * g + r;
        wih[r] = W_ih[row] * L2E2;
        bw[r]  = (b_ih[row] + b_hh[row]) * L2E2;
    }

    // ---- exchange addresses (word granularity), per group ----
    const int exbase = g * GSTR + s * 10;
    unsigned* const wrA[2] = {&ex[0][0][exbase + 2 * w], &ex[0][1][exbase + 2 * w]};
    unsigned* const wrB[2] = {&ex[1][0][exbase + 2 * w], &ex[1][1][exbase + 2 * w]};
    const unsigned* const rdA[2] = {&ex[0][0][exbase], &ex[0][1][exbase]};
    const unsigned* const rdB[2] = {&ex[1][0][exbase], &ex[1][1][exbase]};

    // ---- state: h*[r] = h_state[16w+4g+r]; h0 = 0.
    float hA[4] = {0.f, 0.f, 0.f, 0.f};
    float hB[4] = {0.f, 0.f, 0.f, 0.f};

    const float* xg = x + (size_t)sb * T_;       // this block's 32 sample rows
    const float* const xrowA = &xl[s * XSTR];
    const float* const xrowB = &xl[(16 + s) * XSTR];

    for (int q = 0; q < T_ / QT; ++q) {
        // ---- stage pass q: 32 rows x 256 f32, coalesced dwordx4 ----
        __syncthreads();  // all waves done reading the previous pass
        for (int it = tid; it < SPB * (QT / 4); it += 256) {
            const int row = it >> 6;         // 64 float4 chunks per row
            const int c4  = it & 63;
            const float4 v =
                *(const float4*)(xg + (size_t)row * T_ + q * QT + 4 * c4);
            *(float4*)&xl[row * XSTR + 4 * c4] = v;
        }
        __syncthreads();  // pass visible (drains staging loads once per 256 steps)

        for (int t0 = 0; t0 < QT; t0 += 4) {
            const float4 xqA = *(const float4*)(xrowA + t0);
            const float4 xqB = *(const float4*)(xrowB + t0);
            const float xaA[4] = {xqA.x, xqA.y, xqA.z, xqA.w};
            const float xaB[4] = {xqB.x, xqB.y, xqB.z, xqB.w};

#pragma unroll
            for (int j4 = 0; j4 < 4; ++j4) {
                const int buf = j4 & 1;

                // --- publish both groups' h (f16-packed, 8B each) ---
                const u32x2 pkA = {pkrtz(hA[0], hA[1]), pkrtz(hA[2], hA[3])};
                *(u32x2*)wrA[buf] = pkA;
                const u32x2 pkB = {pkrtz(hB[0], hB[1]), pkrtz(hB[2], hB[3])};
                *(u32x2*)wrB[buf] = pkB;

                __syncthreads();  // one barrier steps BOTH groups

                // --- rebuild B operands for both groups (lane-aligned) ---
                const unsigned* rpA = rdA[buf];
                const u32x2 eA0 = *(const u32x2*)(rpA + 0);
                const u32x2 eA1 = *(const u32x2*)(rpA + 2);
                const u32x2 eA2 = *(const u32x2*)(rpA + 4);
                const u32x2 eA3 = *(const u32x2*)(rpA + 6);
                const unsigned* rpB = rdB[buf];
                const u32x2 eB0 = *(const u32x2*)(rpB + 0);
                const u32x2 eB1 = *(const u32x2*)(rpB + 2);
                const u32x2 eB2 = *(const u32x2*)(rpB + 4);
                const u32x2 eB3 = *(const u32x2*)(rpB + 6);
                const u32x4 qA0 = {eA0.x, eA0.y, eA1.x, eA1.y};
                const u32x4 qA1 = {eA2.x, eA2.y, eA3.x, eA3.y};
                const u32x4 qB0 = {eB0.x, eB0.y, eB1.x, eB1.y};
                const u32x4 qB1 = {eB2.x, eB2.y, eB3.x, eB3.y};
                const f16x8 bA0 = __builtin_bit_cast(f16x8, qA0);
                const f16x8 bA1 = __builtin_bit_cast(f16x8, qA1);
                const f16x8 bB0 = __builtin_bit_cast(f16x8, qB0);
                const f16x8 bB1 = __builtin_bit_cast(f16x8, qB1);

                // --- group A: ci + 2 chained MFMA (r7 form) ---
                f32x4 ciA;
#pragma unroll
                for (int r = 0; r < 4; ++r) ciA[r] = fmaf(xaA[j4], wih[r], bw[r]);
                const f32x4 pA0 =
                    __builtin_amdgcn_mfma_f32_16x16x32_f16(a0, bA0, ciA, 0, 0, 0);
                const f32x4 accA =
                    __builtin_amdgcn_mfma_f32_16x16x32_f16(a1, bA1, pA0, 0, 0, 0);

                // --- group B: ci + 2 chained MFMA ---
                f32x4 ciB;
#pragma unroll
                for (int r = 0; r < 4; ++r) ciB[r] = fmaf(xaB[j4], wih[r], bw[r]);
                const f32x4 pB0 =
                    __builtin_amdgcn_mfma_f32_16x16x32_f16(a0, bB0, ciB, 0, 0, 0);
                const f32x4 accB =
                    __builtin_amdgcn_mfma_f32_16x16x32_f16(a1, bB1, pB0, 0, 0, 0);

                // --- tanh both groups: 16 trans total per wave ---
#pragma unroll
                for (int r = 0; r < 4; ++r) {
                    const float eA = __builtin_amdgcn_exp2f(accA[r]);
                    hA[r] = fmaf(-2.0f, __builtin_amdgcn_rcpf(eA + 1.0f), 1.0f);
                }
#pragma unroll
                for (int r = 0; r < 4; ++r) {
                    const float eB = __builtin_amdgcn_exp2f(accB[r]);
                    hB[r] = fmaf(-2.0f, __builtin_amdgcn_rcpf(eB + 1.0f), 1.0f);
                }
            }
        }
    }

    // ---- FC head for both groups ----
    float pA = 0.0f, pB = 0.0f;
#pragma unroll
    for (int r = 0; r < 4; ++r) {
        const float wf = W_fc[16 * w + 4 * g + r];
        pA = fmaf(hA[r], wf, pA);
        pB = fmaf(hB[r], wf, pB);
    }
    pA += __shfl_down(pA, 32); pA += __shfl_down(pA, 16);
    pB += __shfl_down(pB, 32); pB += __shfl_down(pB, 16);
    if (l < 16) { fcb[w][l] = pA; fcb[w][16 + l] = pB; }
    __syncthreads();
    if (tid < SPB)
        out[sb + tid] =
            (fcb[0][tid] + fcb[1][tid]) + (fcb[2][tid] + fcb[3][tid]) + b_fc[0];
}

extern "C" void kernel_launch(void* const* d_in, const int* in_sizes, int n_in,
                              void* d_out, int out_size, void* d_ws, size_t ws_size,
                              hipStream_t stream) {
    const float* x    = (const float*)d_in[0];
    const float* W_ih = (const float*)d_in[1];
    const float* W_hh = (const float*)d_in[2];
    const float* b_ih = (const float*)d_in[3];
    const float* b_hh = (const float*)d_in[4];
    const float* W_fc = (const float*)d_in[5];
    const float* b_fc = (const float*)d_in[6];
    float* out = (float*)d_out;

    rnn_mfma_2g<<<dim3(B_ / SPB), dim3(256), 0, stream>>>(x, W_ih, W_hh, b_ih, b_hh,
                                                          W_fc, b_fc, out);
}

// Round 10
// 415.921 us; speedup vs baseline: 1.3104x; 1.3104x over previous
//
#include <hip/hip_runtime.h>

#define B_ 2048
#define T_ 2048
#define SPW 16    // samples per block (MFMA N dimension)
#define GSTR 162  // per-g word stride in exchange buf (16 samples * 10 + 2 pad)
#define QT 512    // timesteps per x staging quarter
#define XSTR 516  // f32 stride per sample row in x LDS (pad: 2-way banks, 16B aligned)

typedef _Float16 f16x8 __attribute__((ext_vector_type(8)));
typedef float    f32x4 __attribute__((ext_vector_type(4)));
typedef unsigned u32x2 __attribute__((ext_vector_type(2)));
typedef unsigned u32x4 __attribute__((ext_vector_type(4)));

__device__ __forceinline__ unsigned pkrtz(float lo, float hi) {
    return __builtin_bit_cast(unsigned, __builtin_amdgcn_cvt_pkrtz(lo, hi));
}

// Round 10 = round 7 (343 us, proven) + ONE change: the tanh moves its 4
// rcp's off the quarter-rate trans pipe. r9 evidence: the step is a SERIAL
// sum barrier + ds-wait + MFMA + trans(128 cyc) + VALU; appended work does
// not hide it. New tanh (per value): e = exp2(-|y'|) (free -abs modifier,
// 1 trans), d = 1+e in (1,2], rc = 1/d via 1-fma seed (24/17 - 8/17*d, rel
// err <= 1/17) + 2 Newton steps (rel err ~1.2e-5, far below the f16 h
// quantization of 2.4e-4 that dominates absmax), t = 1 - 2*e*rc, sign via
// XOR (tanh odd). Trans pipe per step: 128 -> 64 cyc; +~28 interleavable
// VALU. Everything else byte-for-byte r7 (exchange layout, 1 barrier/step,
// chained MFMA, ci post-barrier, x LDS staging, sigma-relabeling
// [HW-verified r3-r9]).
__global__ __launch_bounds__(256)
void rnn_mfma_4w5(
    const float* __restrict__ x, const float* __restrict__ W_ih,
    const float* __restrict__ W_hh, const float* __restrict__ b_ih,
    const float* __restrict__ b_hh, const float* __restrict__ W_fc,
    const float* __restrict__ b_fc, float* __restrict__ out)
{
    __shared__ __align__(16) float xl[SPW * XSTR];      // 33 KB x quarter
    __shared__ __align__(16) unsigned ex[2][4 * GSTR];  // [buf][g][s][10 words]
    __shared__ float fcb[4][SPW];

    const int tid = threadIdx.x;
    const int w = tid >> 6;          // wave index == tile index (rows 16w+..)
    const int l = tid & 63;
    const int s = l & 15;            // sample column (C-col / A-M-row / B-N)
    const int g = l >> 4;            // slot group; C row-quad selector
    const int sb = blockIdx.x * SPW;
    const float L2E2 = 2.8853900817779268f;  // 2*log2(e), folded into W/bias

    // ---- A-frags for tile w: slot (g,j) of chunk c holds
    // k = sigma_c(g,j) = 16*(2c+(j>>2)) + 4g + (j&3).   [HW-verified r3-r9]
    f16x8 a0, a1;
#pragma unroll
    for (int j = 0; j < 8; ++j) {
        const int k0 = 16 * (0 + (j >> 2)) + 4 * g + (j & 3);
        const int k1 = 16 * (2 + (j >> 2)) + 4 * g + (j & 3);
        a0[j] = (_Float16)(W_hh[(16 * w + s) * 64 + k0] * L2E2);
        a1[j] = (_Float16)(W_hh[(16 * w + s) * 64 + k1] * L2E2);
    }

    // ---- per-lane C-slot constants: rows 16w + 4g + r
    float wih[4], bw[4];
#pragma unroll
    for (int r = 0; r < 4; ++r) {
        const int row = 16 * w + 4 * g + r;
        wih[r] = W_ih[row] * L2E2;
        bw[r]  = (b_ih[row] + b_hh[row]) * L2E2;
    }

    // ---- exchange addresses (word granularity) ----
    const int exbase = g * GSTR + s * 10;  // this lane's sample slot
    unsigned* const wr0 = &ex[0][exbase + 2 * w];
    unsigned* const wr1 = &ex[1][exbase + 2 * w];
    const unsigned* const rd0 = &ex[0][exbase];
    const unsigned* const rd1 = &ex[1][exbase];

    // ---- state: h[r] = h_state[16w+4g+r] for sample s; h0 = 0.
    float h[4] = {0.0f, 0.0f, 0.0f, 0.0f};

    const float* xg = x + (size_t)sb * T_;  // this block's 16 sample rows
    const float* const xrow = &xl[s * XSTR];

    for (int q = 0; q < 4; ++q) {
        // ---- stage quarter q: 16 rows x 512 f32, coalesced dwordx4 ----
        __syncthreads();  // all waves done reading the previous quarter
        for (int it = tid; it < SPW * (QT / 4); it += 256) {
            const int row = it >> 7;         // 128 float4 chunks per row
            const int c4  = it & 127;
            const float4 v =
                *(const float4*)(xg + (size_t)row * T_ + q * QT + 4 * c4);
            *(float4*)&xl[row * XSTR + 4 * c4] = v;
        }
        __syncthreads();  // quarter visible (drains the staging loads once)

        for (int t0 = 0; t0 < QT; t0 += 4) {
            // group's 4 x values from LDS (lane-private, 2-way banks = free)
            const float4 xq = *(const float4*)(xrow + t0);
            const float xa[4] = {xq.x, xq.y, xq.z, xq.w};

#pragma unroll
            for (int j4 = 0; j4 < 4; ++j4) {
                const int buf = j4 & 1;  // t0 multiple of 4 -> buf = j4&1

                // --- publish this tile's 4 h values (f16-packed, 8B) ---
                const u32x2 pk = {pkrtz(h[0], h[1]), pkrtz(h[2], h[3])};
                *(u32x2*)(buf ? wr1 : wr0) = pk;
                __syncthreads();  // all tiles' h_t visible (vmcnt already 0)

                // --- rebuild full B operands (lane-aligned (g,s) slot) ---
                const unsigned* rp = buf ? rd1 : rd0;
                const u32x2 e0 = *(const u32x2*)(rp + 0);  // tile 0 pair
                const u32x2 e1 = *(const u32x2*)(rp + 2);  // tile 1 pair
                const u32x2 e2 = *(const u32x2*)(rp + 4);  // tile 2 pair
                const u32x2 e3 = *(const u32x2*)(rp + 6);  // tile 3 pair
                const u32x4 q0 = {e0.x, e0.y, e1.x, e1.y};
                const u32x4 q1 = {e2.x, e2.y, e3.x, e3.y};
                const f16x8 b0 = __builtin_bit_cast(f16x8, q0);  // k =  0..31
                const f16x8 b1 = __builtin_bit_cast(f16x8, q1);  // k = 32..63

                // --- acc init (bias + x*w_ih as C-in) + 2 chained MFMA ---
                f32x4 ci;
#pragma unroll
                for (int r = 0; r < 4; ++r) ci[r] = fmaf(xa[j4], wih[r], bw[r]);
                const f32x4 p0 =
                    __builtin_amdgcn_mfma_f32_16x16x32_f16(a0, b0, ci, 0, 0, 0);
                const f32x4 acc =
                    __builtin_amdgcn_mfma_f32_16x16x32_f16(a1, b1, p0, 0, 0, 0);

                // --- tanh: 1 trans/value; rcp via seed + 2 Newton (VALU) ---
                // e = exp2(-|y'|) in (0,1]; d = 1+e in (1,2];
                // rc = 1/d: seed 24/17 - 8/17*d (rel err <= 1/17), 2 Newtons;
                // t = 1 - 2*e*rc = tanh(|y|); h = t XOR sign(y).
#pragma unroll
                for (int r = 0; r < 4; ++r) {
                    const float y = acc[r];
                    const float e = __builtin_amdgcn_exp2f(-__builtin_fabsf(y));
                    const float d = e + 1.0f;
                    float rc = fmaf(d, -0.47058823529f, 1.41176470588f);
                    rc = rc * fmaf(-d, rc, 2.0f);
                    rc = rc * fmaf(-d, rc, 2.0f);
                    const float t = fmaf(-2.0f * e, rc, 1.0f);
                    const unsigned sgn =
                        __builtin_bit_cast(unsigned, y) & 0x80000000u;
                    h[r] = __builtin_bit_cast(float,
                        __builtin_bit_cast(unsigned, t) ^ sgn);
                }
            }
        }
    }

    // ---- FC head: out[s] = sum_row h[row][s] * W_fc[row] + b_fc ----
    float p = 0.0f;
#pragma unroll
    for (int r = 0; r < 4; ++r) p = fmaf(h[r], W_fc[16 * w + 4 * g + r], p);
    p += __shfl_down(p, 32);
    p += __shfl_down(p, 16);
    if (l < 16) fcb[w][l] = p;
    __syncthreads();
    if (tid < 16)
        out[sb + tid] = (fcb[0][tid] + fcb[1][tid]) + (fcb[2][tid] + fcb[3][tid]) + b_fc[0];
}

extern "C" void kernel_launch(void* const* d_in, const int* in_sizes, int n_in,
                              void* d_out, int out_size, void* d_ws, size_t ws_size,
                              hipStream_t stream) {
    const float* x    = (const float*)d_in[0];
    const float* W_ih = (const float*)d_in[1];
    const float* W_hh = (const float*)d_in[2];
    const float* b_ih = (const float*)d_in[3];
    const float* b_hh = (const float*)d_in[4];
    const float* W_fc = (const float*)d_in[5];
    const float* b_fc = (const float*)d_in[6];
    float* out = (float*)d_out;

    rnn_mfma_4w5<<<dim3(B_ / SPW), dim3(256), 0, stream>>>(x, W_ih, W_hh, b_ih, b_hh,
                                                           W_fc, b_fc, out);
}

// Round 11
// 346.899 us; speedup vs baseline: 1.5711x; 1.1990x over previous
//
#include <hip/hip_runtime.h>

#define B_ 2048
#define T_ 2048
#define SPW 16    // samples per block (MFMA N dimension)
#define GSTR 196  // per-g word stride: 16 slots * 12 words + 4 pad (16B-aligned)
#define QT 512    // timesteps per x staging quarter
#define XSTR 516  // f32 stride per sample row in x LDS (pad: 2-way banks, 16B aligned)

typedef _Float16 f16x8 __attribute__((ext_vector_type(8)));
typedef float    f32x4 __attribute__((ext_vector_type(4)));
typedef unsigned u32x2 __attribute__((ext_vector_type(2)));
typedef unsigned u32x4 __attribute__((ext_vector_type(4)));

__device__ __forceinline__ unsigned pkrtz(float lo, float hi) {
    return __builtin_bit_cast(unsigned, __builtin_amdgcn_cvt_pkrtz(lo, hi));
}

// Round 11 = round 7 (343 us, proven) + two ring cuts. r7-r10 evidence pins
// the serial per-step ring at ~402 cyc: tanh ~150 (8 trans @ quarter-rate) ->
// pk/write ~15 -> barrier ~40 -> ds_read wait ~130 -> 2 chained MFMA ~70.
// Cuts (scheduling/layout only, arithmetic identical):
//  1) exchange slot stride 10 -> 12 words: each lane's 8-word slot is now
//     16B-aligned, so the 4x ds_read_b64 + vector assembly collapse to
//     2x ds_read_b128 (fewer DS issues + one wait unit on the path).
//  2) ci = bias + x*w_ih moved pre-barrier (h-independent; x is in LDS so
//     there is no vmcnt interaction -- the r6 failure mode is absent).
// tanh is r7's exp2+rcp form (r10's Newton variant regressed; reverted).
// sigma-relabeling [HW-verified r3-r10]: slot (g,j) of chunk c <-> k =
// 16*(2c+(j>>2)) + 4g + (j&3); consumer lane (s,g) reads producer lane
// (s,g) of waves 2c,2c+1 -> lane-aligned f16 exchange, double-buffered,
// one barrier per step.
__global__ __launch_bounds__(256)
void rnn_mfma_4w6(
    const float* __restrict__ x, const float* __restrict__ W_ih,
    const float* __restrict__ W_hh, const float* __restrict__ b_ih,
    const float* __restrict__ b_hh, const float* __restrict__ W_fc,
    const float* __restrict__ b_fc, float* __restrict__ out)
{
    __shared__ __align__(16) float xl[SPW * XSTR];      // 33 KB x quarter
    __shared__ __align__(16) unsigned ex[2][4 * GSTR];  // [buf][g][s][12 words]
    __shared__ float fcb[4][SPW];

    const int tid = threadIdx.x;
    const int w = tid >> 6;          // wave index == tile index (rows 16w+..)
    const int l = tid & 63;
    const int s = l & 15;            // sample column (C-col / A-M-row / B-N)
    const int g = l >> 4;            // slot group; C row-quad selector
    const int sb = blockIdx.x * SPW;
    const float L2E2 = 2.8853900817779268f;  // 2*log2(e), folded into W/bias

    // ---- A-frags for tile w: slot (g,j) of chunk c holds
    // k = sigma_c(g,j) = 16*(2c+(j>>2)) + 4g + (j&3).   [HW-verified r3-r10]
    f16x8 a0, a1;
#pragma unroll
    for (int j = 0; j < 8; ++j) {
        const int k0 = 16 * (0 + (j >> 2)) + 4 * g + (j & 3);
        const int k1 = 16 * (2 + (j >> 2)) + 4 * g + (j & 3);
        a0[j] = (_Float16)(W_hh[(16 * w + s) * 64 + k0] * L2E2);
        a1[j] = (_Float16)(W_hh[(16 * w + s) * 64 + k1] * L2E2);
    }

    // ---- per-lane C-slot constants: rows 16w + 4g + r
    float wih[4], bw[4];
#pragma unroll
    for (int r = 0; r < 4; ++r) {
        const int row = 16 * w + 4 * g + r;
        wih[r] = W_ih[row] * L2E2;
        bw[r]  = (b_ih[row] + b_hh[row]) * L2E2;
    }

    // ---- exchange addresses (word granularity) ----
    // Lane slot = 12 words (16B-aligned): tiles' pairs at words 2m (m=0..3),
    // words 8-11 pad. Consumer reads words 0-3 (b128 -> chunk 0) and 4-7
    // (b128 -> chunk 1).
    const int exbase = g * GSTR + s * 12;
    unsigned* const wr0 = &ex[0][exbase + 2 * w];
    unsigned* const wr1 = &ex[1][exbase + 2 * w];
    const unsigned* const rd0 = &ex[0][exbase];
    const unsigned* const rd1 = &ex[1][exbase];

    // ---- state: h[r] = h_state[16w+4g+r] for sample s; h0 = 0.
    float h[4] = {0.0f, 0.0f, 0.0f, 0.0f};

    const float* xg = x + (size_t)sb * T_;  // this block's 16 sample rows
    const float* const xrow = &xl[s * XSTR];

    for (int q = 0; q < 4; ++q) {
        // ---- stage quarter q: 16 rows x 512 f32, coalesced dwordx4 ----
        __syncthreads();  // all waves done reading the previous quarter
        for (int it = tid; it < SPW * (QT / 4); it += 256) {
            const int row = it >> 7;         // 128 float4 chunks per row
            const int c4  = it & 127;
            const float4 v =
                *(const float4*)(xg + (size_t)row * T_ + q * QT + 4 * c4);
            *(float4*)&xl[row * XSTR + 4 * c4] = v;
        }
        __syncthreads();  // quarter visible (drains the staging loads once)

        for (int t0 = 0; t0 < QT; t0 += 4) {
            // group's 4 x values from LDS (lane-private, 2-way banks = free)
            const float4 xq = *(const float4*)(xrow + t0);
            const float xa[4] = {xq.x, xq.y, xq.z, xq.w};

#pragma unroll
            for (int j4 = 0; j4 < 4; ++j4) {
                const int buf = j4 & 1;  // t0 multiple of 4 -> buf = j4&1

                // --- publish this tile's 4 h values (f16-packed, 8B) ---
                const u32x2 pk = {pkrtz(h[0], h[1]), pkrtz(h[2], h[3])};
                *(u32x2*)(buf ? wr1 : wr0) = pk;

                // --- h-independent affine fills the pre-barrier window ---
                f32x4 ci;
#pragma unroll
                for (int r = 0; r < 4; ++r) ci[r] = fmaf(xa[j4], wih[r], bw[r]);

                __syncthreads();  // all tiles' h_t visible (vmcnt already 0)

                // --- rebuild B operands: 2x ds_read_b128, lane-aligned ---
                const unsigned* rp = buf ? rd1 : rd0;
                const u32x4 q0 = *(const u32x4*)(rp + 0);  // tiles 0,1: k 0..31
                const u32x4 q1 = *(const u32x4*)(rp + 4);  // tiles 2,3: k 32..63
                const f16x8 b0 = __builtin_bit_cast(f16x8, q0);
                const f16x8 b1 = __builtin_bit_cast(f16x8, q1);

                // --- 2 chained MFMA (C-in carries bias + x*w_ih) ---
                const f32x4 p0 =
                    __builtin_amdgcn_mfma_f32_16x16x32_f16(a0, b0, ci, 0, 0, 0);
                const f32x4 acc =
                    __builtin_amdgcn_mfma_f32_16x16x32_f16(a1, b1, p0, 0, 0, 0);

                // --- tanh(pre) = 1 - 2/(exp2(2log2e*pre)+1): 8 trans ---
#pragma unroll
                for (int r = 0; r < 4; ++r) {
                    const float e = __builtin_amdgcn_exp2f(acc[r]);
                    h[r] = fmaf(-2.0f, __builtin_amdgcn_rcpf(e + 1.0f), 1.0f);
                }
            }
        }
    }

    // ---- FC head: out[s] = sum_row h[row][s] * W_fc[row] + b_fc ----
    float p = 0.0f;
#pragma unroll
    for (int r = 0; r < 4; ++r) p = fmaf(h[r], W_fc[16 * w + 4 * g + r], p);
    p += __shfl_down(p, 32);
    p += __shfl_down(p, 16);
    if (l < 16) fcb[w][l] = p;
    __syncthreads();
    if (tid < 16)
        out[sb + tid] = (fcb[0][tid] + fcb[1][tid]) + (fcb[2][tid] + fcb[3][tid]) + b_fc[0];
}

extern "C" void kernel_launch(void* const* d_in, const int* in_sizes, int n_in,
                              void* d_out, int out_size, void* d_ws, size_t ws_size,
                              hipStream_t stream) {
    const float* x    = (const float*)d_in[0];
    const float* W_ih = (const float*)d_in[1];
    const float* W_hh = (const float*)d_in[2];
    const float* b_ih = (const float*)d_in[3];
    const float* b_hh = (const float*)d_in[4];
    const float* W_fc = (const float*)d_in[5];
    const float* b_fc = (const float*)d_in[6];
    float* out = (float*)d_out;

    rnn_mfma_4w6<<<dim3(B_ / SPW), dim3(256), 0, stream>>>(x, W_ih, W_hh, b_ih, b_hh,
                                                           W_fc, b_fc, out);
}